// Round 1
// baseline (744.042 us; speedup 1.0000x reference)
//
#include <hip/hip_runtime.h>
#include <hip/hip_bf16.h>

#define BB 256
#define NN 257
#define NT 256   // tokens per batch (N-1)
#define DD 768
#define KC 8     // K clusters
#define VV 10000
#define ITERS 4

#define CHD 32               // dims per staged chunk (= 128 B = 1 cache line per token)
#define NCH (DD / CHD)       // 24 chunks per sim sweep
#define CF4 (CHD / 4)        // 8 float4 per token per chunk
#define CSTR 193             // cent row stride in float4 (772 dwords)

__device__ __forceinline__ float waveReduceSum(float v) {
#pragma unroll
    for (int off = 32; off > 0; off >>= 1)
        v += __shfl_xor(v, off, 64);
    return v;
}

__device__ __forceinline__ float dot4chain(float4 a, float4 c, float acc) {
    // exact chain from rounds 1-4 (x,y,z,w ascending)
    return fmaf(a.w, c.w, fmaf(a.z, c.z, fmaf(a.y, c.y, fmaf(a.x, c.x, acc))));
}

// Async global->LDS DMA, 16 B per lane, LDS dest = wave-uniform base + lane*16.
__device__ __forceinline__ void gld16(const float* g, void* lds) {
    __builtin_amdgcn_global_load_lds(
        (const __attribute__((address_space(1))) void*)g,
        (__attribute__((address_space(3))) void*)lds,
        16, 0, 0);
}

// One block (1024 threads, 16 waves) per batch. Sim phase streams tokens
// 32-dims-at-a-time for all 256 tokens into a double-buffered LDS chunk via
// global_load_lds DMA (unchanged from the 699us version, byte-for-byte).
//
// Accumulate phase rewritten: masks are precomputed as float {0.0,1.0} pairs
// in LDS (maskF[g][n][2]) and applied with fmaf(v, mk, c1) instead of
// bfe+cmp+cndmask+add. fmaf(v,1.0f,c) == v+c (single rounding, identical to
// v_add) and fmaf(v,0.0f,c) == c (RNE: +0 + -0 = +0), so every accumulator
// chain (c1, tsum/tr) is BIT-IDENTICAL to the passing version; only the
// instruction count changes (~22 -> ~11 issue-cycles per token).
//
// LDS overlay: c1buf (24 KB) + maskF (8 KB) live inside tbuf buffer 0 -- the
// sim phase (token chunks in tbuf) and the mask/accumulate/normalize phases
// (maskF/c1buf) are barrier-separated and each fully rewrites its region
// every iteration, so lifetimes never overlap. Total LDS 141.5 -> 115 KB.
__global__ __launch_bounds__(1024, 4) void kmeans_kernel(
    const float* __restrict__ tokens,
    const float* __restrict__ vc,
    const int* __restrict__ topk,
    float* __restrict__ out_assign,   // (B, 256, 8) float
    float* __restrict__ delta)        // (V) float accumulators (pre-zeroed)
{
    __shared__ float4 cent4[16 * CSTR];       // 48.2 KB  normalized centroids (row = 2k+c)
    __shared__ float4 tbuf4[2 * NT * CF4];    // 64 KB    double-buffered swizzled chunks
    __shared__ float  tsum[DD];               // 3 KB     (persists across iters)
    __shared__ int sidx[KC];

    float* centf = (float*)cent4;
    // ---- overlays inside tbuf buffer 0 (dead during sim, live after it) ----
    float (*c1buf)[DD]    = (float (*)[DD])tbuf4;                        // [KC][DD]  24576 B @ 0
    float (*maskF)[NT][2] = (float (*)[NT][2])((char*)tbuf4 + 24576);    // [4][NT][2] 8192 B @ 24576

    const int b = blockIdx.x;
    const int t = threadIdx.x;
    const int lane = t & 63;
    const int wave = t >> 6;

    if (t < KC) sidx[t] = topk[b * KC + t];
    __syncthreads();

    // ---- gather + L2-normalize 16 initial centroid rows: wave r -> row r
    {
        const int r = wave;
        const int k = r >> 1, c = r & 1;
        const float* src = vc + ((size_t)sidx[k] * 2 + c) * DD;
        float vals[12];
        float ss = 0.f;
#pragma unroll
        for (int j = 0; j < 12; ++j) {
            vals[j] = src[lane + 64 * j];
            ss = fmaf(vals[j], vals[j], ss);
        }
        ss = waveReduceSum(ss);
        float iv = 1.0f / fmaxf(sqrtf(ss), 1e-12f);
#pragma unroll
        for (int j = 0; j < 12; ++j)
            centf[r * 772 + lane + 64 * j] = vals[j] * iv;
    }
    __syncthreads();

    const float* tpb = tokens + ((size_t)b * NN + 1) * DD;

    // sim roles: thread = (token, row-group of 4)
    const int tok = t & 255;
    const int g   = t >> 8;
    const int s7  = tok & 7;

    // DMA lane roles: wave handles chunk slots [wave*128, wave*128+128)
    // slot -> token slot>>3, physical f4 q = slot&7, global col = q ^ (tok&7)
    const int slotA = wave * 128 + lane;         // load 0
    const int slotB = slotA + 64;                // load 1
    const float* gbaseA = tpb + (size_t)(slotA >> 3) * DD + 4 * ((slotA & 7) ^ ((slotA >> 3) & 7));
    const float* gbaseB = tpb + (size_t)(slotB >> 3) * DD + 4 * ((slotB & 7) ^ ((slotB >> 3) & 7));

    for (int it = 0; it < ITERS; ++it) {
        float acc[4] = {0.f, 0.f, 0.f, 0.f};

        // prologue: DMA chunk 0 into buffer 0
        gld16(gbaseA, (void*)(tbuf4 + wave * 128));
        gld16(gbaseB, (void*)(tbuf4 + wave * 128 + 64));

        for (int cix = 0; cix < NCH; ++cix) {
            __syncthreads();   // drains vmcnt -> buf[cix&1] complete & visible
            if (cix + 1 < NCH) {
                const int nb = (cix + 1) & 1;
                gld16(gbaseA + (cix + 1) * CHD, (void*)(tbuf4 + nb * 2048 + wave * 128));
                gld16(gbaseB + (cix + 1) * CHD, (void*)(tbuf4 + nb * 2048 + wave * 128 + 64));
            }
            // ---- consume chunk cix: advance the 4 row chains over 32 dims
            {
                const float4* tb = tbuf4 + (cix & 1) * 2048 + (tok << 3);
                const float4* cr = cent4 + (g * 4) * CSTR + (cix << 3);
#pragma unroll
                for (int j4 = 0; j4 < CF4; ++j4) {
                    float4 a  = tb[j4 ^ s7];            // conflict-free swizzled b128
                    float4 c0 = cr[j4];                 // wave-uniform broadcasts
                    float4 c1 = cr[CSTR + j4];
                    float4 c2 = cr[2 * CSTR + j4];
                    float4 c3 = cr[3 * CSTR + j4];
                    acc[0] = dot4chain(a, c0, acc[0]);
                    acc[1] = dot4chain(a, c1, acc[1]);
                    acc[2] = dot4chain(a, c2, acc[2]);
                    acc[3] = dot4chain(a, c3, acc[3]);
                }
            }
        }

        // ---- masks: write float {0,1} pair for clusters (2g, 2g+1) directly
        // (same comparisons as the passing version: ties -> 0)
        {
            float2 mf;
            mf.x = (acc[1] > acc[0]) ? 1.f : 0.f;    // cluster 2g
            mf.y = (acc[3] > acc[2]) ? 1.f : 0.f;    // cluster 2g+1
            *(float2*)&maskF[g][tok][0] = mf;
        }
        __syncthreads();

        if (it == ITERS - 1 && t < NT) {
            // out values ARE the mask floats, same bit order as before
            float4 o0 = make_float4(maskF[0][t][0], maskF[0][t][1],
                                    maskF[1][t][0], maskF[1][t][1]);
            float4 o1 = make_float4(maskF[2][t][0], maskF[2][t][1],
                                    maskF[3][t][0], maskF[3][t][1]);
            float4* op = (float4*)(out_assign + ((size_t)b * NT + t) * KC);
            op[0] = o0; op[1] = o1;
        }
        // no barrier needed: maskF is read-only from here to the next barrier

        // ============ accumulate phase: fmaf with float masks ============
        {
            const int tt = t & 255;
            const float* mfp = &maskF[g][0][0];     // wave-uniform row
            float c1[3][2] = {{0.f, 0.f}, {0.f, 0.f}, {0.f, 0.f}};
            float tr0 = 0.f, tr1 = 0.f, tr2 = 0.f;
#pragma unroll 4
            for (int n = 0; n < NT; n += 2) {
                const float* rn = tpb + (size_t)n * DD;
                float v0 = rn[tt], v1 = rn[tt + 256], v2 = rn[tt + 512];          // coalesced
                float w0 = rn[DD + tt], w1 = rn[DD + tt + 256], w2 = rn[DD + tt + 512];
                float4 mk = *(const float4*)(mfp + 2 * n);   // masks for n (x,y) and n+1 (z,w)
                // n: bit-identical to (on ? v : 0) + add
                c1[0][0] = fmaf(v0, mk.x, c1[0][0]);
                c1[1][0] = fmaf(v1, mk.x, c1[1][0]);
                c1[2][0] = fmaf(v2, mk.x, c1[2][0]);
                c1[0][1] = fmaf(v0, mk.y, c1[0][1]);
                c1[1][1] = fmaf(v1, mk.y, c1[1][1]);
                c1[2][1] = fmaf(v2, mk.y, c1[2][1]);
                // n+1
                c1[0][0] = fmaf(w0, mk.z, c1[0][0]);
                c1[1][0] = fmaf(w1, mk.z, c1[1][0]);
                c1[2][0] = fmaf(w2, mk.z, c1[2][0]);
                c1[0][1] = fmaf(w0, mk.w, c1[0][1]);
                c1[1][1] = fmaf(w1, mk.w, c1[1][1]);
                c1[2][1] = fmaf(w2, mk.w, c1[2][1]);
                if (it == 0 && g == 0) {
                    tr0 += v0; tr1 += v1; tr2 += v2;    // n-ascending, same chain
                    tr0 += w0; tr1 += w1; tr2 += w2;
                }
            }
#pragma unroll
            for (int i = 0; i < 3; ++i)
#pragma unroll
                for (int kk = 0; kk < 2; ++kk)
                    c1buf[2 * g + kk][tt + 256 * i] = c1[i][kk];
            if (it == 0 && g == 0) {
                tsum[tt] = tr0; tsum[tt + 256] = tr1; tsum[tt + 512] = tr2;
            }
        }
        __syncthreads();

        // ============ normalize phase: wave r -> row r (= 2k+cc) ============
        {
            const int k = wave >> 1, cc = wave & 1;
            float vals[12];
            float ss = 0.f;
#pragma unroll
            for (int j = 0; j < 12; ++j) {
                int d = lane + 64 * j;
                float c1v = c1buf[k][d];
                float v = cc ? c1v : (tsum[d] - c1v);
                vals[j] = v;
                ss = fmaf(v, v, ss);
            }
            ss = waveReduceSum(ss);
            float iv = 1.0f / fmaxf(sqrtf(ss), 1e-12f);
#pragma unroll
            for (int j = 0; j < 12; ++j)
                centf[wave * 772 + lane + 64 * j] = vals[j] * iv;
        }
        __syncthreads();   // cent ready; tbuf (incl. c1buf/maskF overlay) free for next iter
    }

    // ---- scatter: vc[idx,0,0] += centroids_final[b,k,0,0] (c0 row, element 0)
    if (t < KC) {
        atomicAdd(delta + sidx[t], centf[(2 * t) * 772]);
    }
}

__global__ __launch_bounds__(1024) void vcnorm_kernel(
    const float* __restrict__ vc,
    const float* __restrict__ delta,
    float* __restrict__ out)          // (V, 2, D)
{
    const int t = threadIdx.x;
    const int lane = t & 63;
    const int wave = t >> 6;
    const int r = blockIdx.x * 16 + wave;     // row in [0, 2V)
    if (r >= 2 * VV) return;
    const int v = r >> 1;
    const int c = r & 1;
    const float* src = vc + (size_t)r * DD;
    float4 x[3];
#pragma unroll
    for (int j = 0; j < 3; ++j)
        x[j] = *(const float4*)(src + (lane + 64 * j) * 4);
    if (c == 0 && lane == 0) x[0].x += delta[v];
    float ss = 0.f;
#pragma unroll
    for (int j = 0; j < 3; ++j)
        ss += x[j].x * x[j].x + x[j].y * x[j].y + x[j].z * x[j].z + x[j].w * x[j].w;
    ss = waveReduceSum(ss);
    float iv = 1.0f / fmaxf(sqrtf(ss), 1e-12f);
    float* dst = out + (size_t)r * DD;
#pragma unroll
    for (int j = 0; j < 3; ++j) {
        float4 y = make_float4(x[j].x * iv, x[j].y * iv, x[j].z * iv, x[j].w * iv);
        *(float4*)(dst + (lane + 64 * j) * 4) = y;
    }
}

extern "C" void kernel_launch(void* const* d_in, const int* in_sizes, int n_in,
                              void* d_out, int out_size, void* d_ws, size_t ws_size,
                              hipStream_t stream) {
    const float* tokens = (const float*)d_in[0];
    const float* vc     = (const float*)d_in[1];
    const int*   topk   = (const int*)d_in[2];
    float* out          = (float*)d_out;
    float* assignments  = out;                                   // B*NT*KC floats
    float* vcnew        = out + (size_t)BB * NT * KC;            // V*2*D floats
    float* delta        = (float*)d_ws;                          // V floats

    hipMemsetAsync(delta, 0, VV * sizeof(float), stream);
    hipLaunchKernelGGL(kmeans_kernel, dim3(BB), dim3(1024), 0, stream,
                       tokens, vc, topk, assignments, delta);
    hipLaunchKernelGGL(vcnorm_kernel, dim3((2 * VV + 15) / 16), dim3(1024), 0, stream,
                       vc, delta, vcnew);
}

// Round 2
// 681.436 us; speedup vs baseline: 1.0919x; 1.0919x over previous
//
#include <hip/hip_runtime.h>
#include <hip/hip_bf16.h>

#define BB 256
#define NN 257
#define NT 256   // tokens per batch (N-1)
#define DD 768
#define KC 8     // K clusters
#define VV 10000
#define ITERS 4

#define CHD 32               // dims per staged chunk (= 128 B = 1 cache line per token)
#define NCH (DD / CHD)       // 24 chunks per sim sweep
#define CF4 (CHD / 4)        // 8 float4 per token per chunk
#define CSTR 193             // cent row stride in float4 (772 dwords)

__device__ __forceinline__ float waveReduceSum(float v) {
#pragma unroll
    for (int off = 32; off > 0; off >>= 1)
        v += __shfl_xor(v, off, 64);
    return v;
}

__device__ __forceinline__ float dot4chain(float4 a, float4 c, float acc) {
    // exact chain from rounds 1-4 (x,y,z,w ascending)
    return fmaf(a.w, c.w, fmaf(a.z, c.z, fmaf(a.y, c.y, fmaf(a.x, c.x, acc))));
}

// Async global->LDS DMA, 16 B per lane, LDS dest = wave-uniform base + lane*16.
__device__ __forceinline__ void gld16(const float* g, void* lds) {
    __builtin_amdgcn_global_load_lds(
        (const __attribute__((address_space(1))) void*)g,
        (__attribute__((address_space(3))) void*)lds,
        16, 0, 0);
}

// One block (1024 threads, 16 waves) per batch. Sim phase (unchanged since the
// 699us kernel): streams tokens 32-dims-at-a-time into a double-buffered LDS
// chunk via global_load_lds DMA, swizzled on the global side so sim's
// lane-per-token b128 reads are conflict-free.
//
// Accumulate phase repartitioned (R2): thread t<768 owns dim d=t and ALL 8
// cluster accumulators. Each token value is loaded from global ONCE per block
// (was 4x: each of the 4 g-groups swept the whole row) -> accumulate traffic
// drops 3.1 MB -> 786 KB per block-iter, load instructions drop 4x, fma count
// and per-SIMD fma cycles unchanged (waves 12-15 idle = 1 per SIMD). Masks are
// float {0,1} in LDS laid out [NT][8]; applied with fmaf(v, m, acc):
// fmaf(v,1,c)==v+c (single rounding) and fmaf(v,0,c)==c (RNE absorbs -0), so
// every c1 chain is the n-ascending chain of the passing kernel, bit-identical.
// tsum rides along for free (value already in register, same n-ascending adds).
//
// LDS overlay: c1buf (24 KB) + maskF (8 KB) live inside tbuf buffer 0 -- sim
// (tokens in tbuf) and mask/accumulate/normalize (maskF/c1buf) are
// barrier-separated and each fully rewrites its region every iteration.
__global__ __launch_bounds__(1024, 4) void kmeans_kernel(
    const float* __restrict__ tokens,
    const float* __restrict__ vc,
    const int* __restrict__ topk,
    float* __restrict__ out_assign,   // (B, 256, 8) float
    float* __restrict__ delta)        // (V) float accumulators (pre-zeroed)
{
    __shared__ float4 cent4[16 * CSTR];       // 48.2 KB  normalized centroids (row = 2k+c)
    __shared__ float4 tbuf4[2 * NT * CF4];    // 64 KB    double-buffered swizzled chunks
    __shared__ float  tsum[DD];               // 3 KB     (persists across iters)
    __shared__ int sidx[KC];

    float* centf = (float*)cent4;
    // ---- overlays inside tbuf buffer 0 (dead during sim, live after it) ----
    float (*c1buf)[DD] = (float (*)[DD])tbuf4;                     // [KC][DD]  24576 B @ 0
    float (*maskF)[KC] = (float (*)[KC])((char*)tbuf4 + 24576);    // [NT][8]    8192 B @ 24576

    const int b = blockIdx.x;
    const int t = threadIdx.x;
    const int lane = t & 63;
    const int wave = t >> 6;

    if (t < KC) sidx[t] = topk[b * KC + t];
    __syncthreads();

    // ---- gather + L2-normalize 16 initial centroid rows: wave r -> row r
    {
        const int r = wave;
        const int k = r >> 1, c = r & 1;
        const float* src = vc + ((size_t)sidx[k] * 2 + c) * DD;
        float vals[12];
        float ss = 0.f;
#pragma unroll
        for (int j = 0; j < 12; ++j) {
            vals[j] = src[lane + 64 * j];
            ss = fmaf(vals[j], vals[j], ss);
        }
        ss = waveReduceSum(ss);
        float iv = 1.0f / fmaxf(sqrtf(ss), 1e-12f);
#pragma unroll
        for (int j = 0; j < 12; ++j)
            centf[r * 772 + lane + 64 * j] = vals[j] * iv;
    }
    __syncthreads();

    const float* tpb = tokens + ((size_t)b * NN + 1) * DD;

    // sim roles: thread = (token, row-group of 4)
    const int tok = t & 255;
    const int g   = t >> 8;
    const int s7  = tok & 7;

    // DMA lane roles: wave handles chunk slots [wave*128, wave*128+128)
    // slot -> token slot>>3, physical f4 q = slot&7, global col = q ^ (tok&7)
    const int slotA = wave * 128 + lane;         // load 0
    const int slotB = slotA + 64;                // load 1
    const float* gbaseA = tpb + (size_t)(slotA >> 3) * DD + 4 * ((slotA & 7) ^ ((slotA >> 3) & 7));
    const float* gbaseB = tpb + (size_t)(slotB >> 3) * DD + 4 * ((slotB & 7) ^ ((slotB >> 3) & 7));

    for (int it = 0; it < ITERS; ++it) {
        float acc[4] = {0.f, 0.f, 0.f, 0.f};

        // prologue: DMA chunk 0 into buffer 0
        gld16(gbaseA, (void*)(tbuf4 + wave * 128));
        gld16(gbaseB, (void*)(tbuf4 + wave * 128 + 64));

        for (int cix = 0; cix < NCH; ++cix) {
            __syncthreads();   // drains vmcnt -> buf[cix&1] complete & visible
            if (cix + 1 < NCH) {
                const int nb = (cix + 1) & 1;
                gld16(gbaseA + (cix + 1) * CHD, (void*)(tbuf4 + nb * 2048 + wave * 128));
                gld16(gbaseB + (cix + 1) * CHD, (void*)(tbuf4 + nb * 2048 + wave * 128 + 64));
            }
            // ---- consume chunk cix: advance the 4 row chains over 32 dims
            {
                const float4* tb = tbuf4 + (cix & 1) * 2048 + (tok << 3);
                const float4* cr = cent4 + (g * 4) * CSTR + (cix << 3);
#pragma unroll
                for (int j4 = 0; j4 < CF4; ++j4) {
                    float4 a  = tb[j4 ^ s7];            // conflict-free swizzled b128
                    float4 c0 = cr[j4];                 // wave-uniform broadcasts
                    float4 c1 = cr[CSTR + j4];
                    float4 c2 = cr[2 * CSTR + j4];
                    float4 c3 = cr[3 * CSTR + j4];
                    acc[0] = dot4chain(a, c0, acc[0]);
                    acc[1] = dot4chain(a, c1, acc[1]);
                    acc[2] = dot4chain(a, c2, acc[2]);
                    acc[3] = dot4chain(a, c3, acc[3]);
                }
            }
        }

        // ---- masks: thread (g,tok) writes float {0,1} for clusters (2g, 2g+1)
        // (same comparisons as the passing version: ties -> 0)
        {
            float2 mf;
            mf.x = (acc[1] > acc[0]) ? 1.f : 0.f;    // cluster 2g
            mf.y = (acc[3] > acc[2]) ? 1.f : 0.f;    // cluster 2g+1
            *(float2*)&maskF[tok][2 * g] = mf;
        }
        __syncthreads();

        if (it == ITERS - 1 && t < NT) {
            // out values ARE the mask floats, cluster order 0..7
            const float4* mf4 = (const float4*)&maskF[t][0];
            float4* op = (float4*)(out_assign + ((size_t)b * NT + t) * KC);
            op[0] = mf4[0]; op[1] = mf4[1];
        }
        // no barrier needed: maskF is read-only from here to the next barrier

        // ============ accumulate: thread t<768 owns dim d=t, all 8 clusters ====
        if (t < DD) {
            const int d = t;
            const float* col = tpb + d;
            const float4* mrow = (const float4*)&maskF[0][0];   // 2 float4 per token
            float a0 = 0.f, a1 = 0.f, a2 = 0.f, a3 = 0.f;
            float a4 = 0.f, a5 = 0.f, a6 = 0.f, a7 = 0.f;
            float tr = 0.f;
            for (int n0 = 0; n0 < NT; n0 += 16) {
                float v[16];
#pragma unroll
                for (int u = 0; u < 16; ++u)
                    v[u] = col[(size_t)(n0 + u) * DD];          // coalesced 256B/wave
#pragma unroll
                for (int u = 0; u < 16; ++u) {
                    float4 ma = mrow[2 * (n0 + u)];             // wave-uniform broadcast
                    float4 mb = mrow[2 * (n0 + u) + 1];
                    a0 = fmaf(v[u], ma.x, a0);
                    a1 = fmaf(v[u], ma.y, a1);
                    a2 = fmaf(v[u], ma.z, a2);
                    a3 = fmaf(v[u], ma.w, a3);
                    a4 = fmaf(v[u], mb.x, a4);
                    a5 = fmaf(v[u], mb.y, a5);
                    a6 = fmaf(v[u], mb.z, a6);
                    a7 = fmaf(v[u], mb.w, a7);
                    if (it == 0) tr += v[u];                    // n-ascending, same chain
                }
            }
            c1buf[0][d] = a0; c1buf[1][d] = a1; c1buf[2][d] = a2; c1buf[3][d] = a3;
            c1buf[4][d] = a4; c1buf[5][d] = a5; c1buf[6][d] = a6; c1buf[7][d] = a7;
            if (it == 0) tsum[d] = tr;
        }
        __syncthreads();

        // ============ normalize phase: wave r -> row r (= 2k+cc) ============
        {
            const int k = wave >> 1, cc = wave & 1;
            float vals[12];
            float ss = 0.f;
#pragma unroll
            for (int j = 0; j < 12; ++j) {
                int d = lane + 64 * j;
                float c1v = c1buf[k][d];
                float v = cc ? c1v : (tsum[d] - c1v);
                vals[j] = v;
                ss = fmaf(v, v, ss);
            }
            ss = waveReduceSum(ss);
            float iv = 1.0f / fmaxf(sqrtf(ss), 1e-12f);
#pragma unroll
            for (int j = 0; j < 12; ++j)
                centf[wave * 772 + lane + 64 * j] = vals[j] * iv;
        }
        __syncthreads();   // cent ready; tbuf (incl. c1buf/maskF overlay) free for next iter
    }

    // ---- scatter: vc[idx,0,0] += centroids_final[b,k,0,0] (c0 row, element 0)
    if (t < KC) {
        atomicAdd(delta + sidx[t], centf[(2 * t) * 772]);
    }
}

__global__ __launch_bounds__(1024) void vcnorm_kernel(
    const float* __restrict__ vc,
    const float* __restrict__ delta,
    float* __restrict__ out)          // (V, 2, D)
{
    const int t = threadIdx.x;
    const int lane = t & 63;
    const int wave = t >> 6;
    const int r = blockIdx.x * 16 + wave;     // row in [0, 2V)
    if (r >= 2 * VV) return;
    const int v = r >> 1;
    const int c = r & 1;
    const float* src = vc + (size_t)r * DD;
    float4 x[3];
#pragma unroll
    for (int j = 0; j < 3; ++j)
        x[j] = *(const float4*)(src + (lane + 64 * j) * 4);
    if (c == 0 && lane == 0) x[0].x += delta[v];
    float ss = 0.f;
#pragma unroll
    for (int j = 0; j < 3; ++j)
        ss += x[j].x * x[j].x + x[j].y * x[j].y + x[j].z * x[j].z + x[j].w * x[j].w;
    ss = waveReduceSum(ss);
    float iv = 1.0f / fmaxf(sqrtf(ss), 1e-12f);
    float* dst = out + (size_t)r * DD;
#pragma unroll
    for (int j = 0; j < 3; ++j) {
        float4 y = make_float4(x[j].x * iv, x[j].y * iv, x[j].z * iv, x[j].w * iv);
        *(float4*)(dst + (lane + 64 * j) * 4) = y;
    }
}

extern "C" void kernel_launch(void* const* d_in, const int* in_sizes, int n_in,
                              void* d_out, int out_size, void* d_ws, size_t ws_size,
                              hipStream_t stream) {
    const float* tokens = (const float*)d_in[0];
    const float* vc     = (const float*)d_in[1];
    const int*   topk   = (const int*)d_in[2];
    float* out          = (float*)d_out;
    float* assignments  = out;                                   // B*NT*KC floats
    float* vcnew        = out + (size_t)BB * NT * KC;            // V*2*D floats
    float* delta        = (float*)d_ws;                          // V floats

    hipMemsetAsync(delta, 0, VV * sizeof(float), stream);
    hipLaunchKernelGGL(kmeans_kernel, dim3(BB), dim3(1024), 0, stream,
                       tokens, vc, topk, assignments, delta);
    hipLaunchKernelGGL(vcnorm_kernel, dim3((2 * VV + 15) / 16), dim3(1024), 0, stream,
                       vc, delta, vcnew);
}

// Round 3
// 648.617 us; speedup vs baseline: 1.1471x; 1.0506x over previous
//
#include <hip/hip_runtime.h>
#include <hip/hip_bf16.h>

#define BB 256
#define NN 257
#define NT 256   // tokens per batch (N-1)
#define DD 768
#define KC 8     // K clusters
#define VV 10000
#define ITERS 4

#define CHD 32               // dims per staged chunk (= 128 B = 1 cache line per token)
#define NCH (DD / CHD)       // 24 chunks per sim sweep
#define CF4 (CHD / 4)        // 8 float4 per token per chunk
#define CSTR 193             // cent row stride in float4 (772 dwords)

__device__ __forceinline__ float waveReduceSum(float v) {
#pragma unroll
    for (int off = 32; off > 0; off >>= 1)
        v += __shfl_xor(v, off, 64);
    return v;
}

__device__ __forceinline__ float dot4chain(float4 a, float4 c, float acc) {
    // exact chain from rounds 1-4 (x,y,z,w ascending)
    return fmaf(a.w, c.w, fmaf(a.z, c.z, fmaf(a.y, c.y, fmaf(a.x, c.x, acc))));
}

// Async global->LDS DMA, 16 B per lane, LDS dest = wave-uniform base + lane*16.
__device__ __forceinline__ void gld16(const float* g, void* lds) {
    __builtin_amdgcn_global_load_lds(
        (const __attribute__((address_space(1))) void*)g,
        (__attribute__((address_space(3))) void*)lds,
        16, 0, 0);
}

// One block (1024 threads, 16 waves) per batch.
//
// R3 changes vs the 455us/dispatch version:
// 1. Sim loop: TRIPLE-buffered chunk DMA with counted vmcnt (T3/T4). The old
//    __syncthreads() per chunk drained vmcnt(0), stalling all 16 waves on a
//    DMA issued only ~1 consume-phase (~350cy) earlier vs ~900cy HBM latency.
//    Now: s_waitcnt vmcnt(2) + raw s_barrier; chunk c+2 is issued AFTER the
//    barrier (the buffer it overwrites, chunk c-1's, is provably past all
//    consumers), giving every DMA ~2 consume-phases in flight. vmcnt is FIFO:
//    vmcnt(2) => only chunk c+1's 2 issues may remain => chunk c complete for
//    this wave; the barrier extends that to all waves. Tail chunk 23 uses one
//    full __syncthreads() drain.
// 2. c1buf + tsum LDS eliminated: accumulate thread d holds a_k and the it-0
//    token sum (tsum_reg, persistent register) and writes BOTH unnormalized
//    rows straight into centf: row 2k+1 = a_k, row 2k = tsum_reg - a_k (the
//    identical subtraction normalize used to do -> bit-identical). Normalize
//    is now an in-place read/reduce/scale of its own centf row. The freed LDS
//    funds the 3rd DMA buffer: cent 49408 + tbuf 98304 = 147.7 KB.
//
// All fp chains (sim j-ascending dot4chain, accumulate n-ascending fmaf with
// {0,1} float masks, c0 = tsum - c1 subtraction, norm fmaf reduce) are
// bit-identical to the passing R2 kernel.
__global__ __launch_bounds__(1024, 4) void kmeans_kernel(
    const float* __restrict__ tokens,
    const float* __restrict__ vc,
    const int* __restrict__ topk,
    float* __restrict__ out_assign,   // (B, 256, 8) float
    float* __restrict__ delta)        // (V) float accumulators (pre-zeroed)
{
    __shared__ float4 cent4[16 * CSTR];       // 48.25 KB normalized centroids (row = 2k+c)
    __shared__ float4 tbuf4[3 * NT * CF4];    // 96 KB    triple-buffered swizzled chunks
    __shared__ int sidx[KC];

    float* centf = (float*)cent4;
    // ---- overlay inside tbuf buffer 0 (dead during sim, live after it) ----
    float (*maskF)[KC] = (float (*)[KC])tbuf4;     // [NT][8] 8192 B @ 0

    const int b = blockIdx.x;
    const int t = threadIdx.x;
    const int lane = t & 63;
    const int wave = t >> 6;

    if (t < KC) sidx[t] = topk[b * KC + t];
    __syncthreads();

    // ---- gather + L2-normalize 16 initial centroid rows: wave r -> row r
    {
        const int r = wave;
        const int k = r >> 1, c = r & 1;
        const float* src = vc + ((size_t)sidx[k] * 2 + c) * DD;
        float vals[12];
        float ss = 0.f;
#pragma unroll
        for (int j = 0; j < 12; ++j) {
            vals[j] = src[lane + 64 * j];
            ss = fmaf(vals[j], vals[j], ss);
        }
        ss = waveReduceSum(ss);
        float iv = 1.0f / fmaxf(sqrtf(ss), 1e-12f);
#pragma unroll
        for (int j = 0; j < 12; ++j)
            centf[r * 772 + lane + 64 * j] = vals[j] * iv;
    }
    __syncthreads();

    const float* tpb = tokens + ((size_t)b * NN + 1) * DD;

    // sim roles: thread = (token, row-group of 4)
    const int tok = t & 255;
    const int g   = t >> 8;
    const int s7  = tok & 7;

    // DMA lane roles: wave handles chunk slots [wave*128, wave*128+128)
    // slot -> token slot>>3, physical f4 q = slot&7, global col = q ^ (tok&7)
    const int slotA = wave * 128 + lane;         // load 0
    const int slotB = slotA + 64;                // load 1
    const float* gbaseA = tpb + (size_t)(slotA >> 3) * DD + 4 * ((slotA & 7) ^ ((slotA >> 3) & 7));
    const float* gbaseB = tpb + (size_t)(slotB >> 3) * DD + 4 * ((slotB & 7) ^ ((slotB >> 3) & 7));

    float tsum_reg = 0.f;   // per-dim token sum, computed it=0, reused it=1..3

    for (int it = 0; it < ITERS; ++it) {
        float acc[4] = {0.f, 0.f, 0.f, 0.f};

        // prologue: DMA chunks 0,1 into buffers 0,1
        gld16(gbaseA,       (void*)(tbuf4 + wave * 128));
        gld16(gbaseB,       (void*)(tbuf4 + wave * 128 + 64));
        gld16(gbaseA + CHD, (void*)(tbuf4 + 2048 + wave * 128));
        gld16(gbaseB + CHD, (void*)(tbuf4 + 2048 + wave * 128 + 64));

#pragma unroll 1
        for (int cix = 0; cix < NCH - 1; ++cix) {
            // chunk cix ready once only chunk cix+1's 2 issues remain (FIFO)
            asm volatile("s_waitcnt vmcnt(2)" ::: "memory");
            __builtin_amdgcn_s_barrier();
            __builtin_amdgcn_sched_barrier(0);
            if (cix + 2 < NCH) {
                const int nb = (cix + 2) % 3;   // overwrites chunk cix-1's buffer: all
                                                // consumers passed the barrier above
                gld16(gbaseA + (cix + 2) * CHD, (void*)(tbuf4 + nb * 2048 + wave * 128));
                gld16(gbaseB + (cix + 2) * CHD, (void*)(tbuf4 + nb * 2048 + wave * 128 + 64));
            }
            // ---- consume chunk cix: advance the 4 row chains over 32 dims
            {
                const float4* tb = tbuf4 + (cix % 3) * 2048 + (tok << 3);
                const float4* cr = cent4 + (g * 4) * CSTR + (cix << 3);
#pragma unroll
                for (int j4 = 0; j4 < CF4; ++j4) {
                    float4 a  = tb[j4 ^ s7];            // conflict-free swizzled b128
                    float4 c0 = cr[j4];                 // wave-uniform broadcasts
                    float4 c1 = cr[CSTR + j4];
                    float4 c2 = cr[2 * CSTR + j4];
                    float4 c3 = cr[3 * CSTR + j4];
                    acc[0] = dot4chain(a, c0, acc[0]);
                    acc[1] = dot4chain(a, c1, acc[1]);
                    acc[2] = dot4chain(a, c2, acc[2]);
                    acc[3] = dot4chain(a, c3, acc[3]);
                }
            }
        }
        // tail: chunk 23 -- full drain is fine once per sweep
        __syncthreads();
        {
            const int cix = NCH - 1;
            const float4* tb = tbuf4 + (cix % 3) * 2048 + (tok << 3);
            const float4* cr = cent4 + (g * 4) * CSTR + (cix << 3);
#pragma unroll
            for (int j4 = 0; j4 < CF4; ++j4) {
                float4 a  = tb[j4 ^ s7];
                float4 c0 = cr[j4];
                float4 c1 = cr[CSTR + j4];
                float4 c2 = cr[2 * CSTR + j4];
                float4 c3 = cr[3 * CSTR + j4];
                acc[0] = dot4chain(a, c0, acc[0]);
                acc[1] = dot4chain(a, c1, acc[1]);
                acc[2] = dot4chain(a, c2, acc[2]);
                acc[3] = dot4chain(a, c3, acc[3]);
            }
        }

        // ---- masks: thread (g,tok) writes float {0,1} for clusters (2g, 2g+1)
        // (maskF lives in buf0 [0,8K): disjoint from chunk 23's buf2; chunk 21
        //  (buf0) consumers all passed the cix=22 barrier)
        {
            float2 mf;
            mf.x = (acc[1] > acc[0]) ? 1.f : 0.f;    // cluster 2g   (ties -> 0)
            mf.y = (acc[3] > acc[2]) ? 1.f : 0.f;    // cluster 2g+1
            *(float2*)&maskF[tok][2 * g] = mf;
        }
        __syncthreads();

        if (it == ITERS - 1 && t < NT) {
            const float4* mf4 = (const float4*)&maskF[t][0];
            float4* op = (float4*)(out_assign + ((size_t)b * NT + t) * KC);
            op[0] = mf4[0]; op[1] = mf4[1];
        }
        // no barrier needed: maskF is read-only from here to the next barrier

        // ==== accumulate: thread t<768 owns dim d=t, all 8 clusters; writes
        // ==== BOTH unnormalized centroid rows (c1 = a_k, c0 = tsum - a_k)
        if (t < DD) {
            const int d = t;
            const float* col = tpb + d;
            const float4* mrow = (const float4*)&maskF[0][0];   // 2 float4 per token
            float a0 = 0.f, a1 = 0.f, a2 = 0.f, a3 = 0.f;
            float a4 = 0.f, a5 = 0.f, a6 = 0.f, a7 = 0.f;
            float tr = 0.f;
            for (int n0 = 0; n0 < NT; n0 += 16) {
                float v[16];
#pragma unroll
                for (int u = 0; u < 16; ++u)
                    v[u] = col[(size_t)(n0 + u) * DD];          // coalesced 256B/wave
#pragma unroll
                for (int u = 0; u < 16; ++u) {
                    float4 ma = mrow[2 * (n0 + u)];             // wave-uniform broadcast
                    float4 mb = mrow[2 * (n0 + u) + 1];
                    a0 = fmaf(v[u], ma.x, a0);
                    a1 = fmaf(v[u], ma.y, a1);
                    a2 = fmaf(v[u], ma.z, a2);
                    a3 = fmaf(v[u], ma.w, a3);
                    a4 = fmaf(v[u], mb.x, a4);
                    a5 = fmaf(v[u], mb.y, a5);
                    a6 = fmaf(v[u], mb.z, a6);
                    a7 = fmaf(v[u], mb.w, a7);
                    if (it == 0) tr += v[u];                    // n-ascending, same chain
                }
            }
            if (it == 0) tsum_reg = tr;
            // rows r=2k+1 get a_k; rows r=2k get tsum-a_k (same subtraction
            // normalize used to perform -> identical values)
            centf[ 1 * 772 + d] = a0;  centf[ 0 * 772 + d] = tsum_reg - a0;
            centf[ 3 * 772 + d] = a1;  centf[ 2 * 772 + d] = tsum_reg - a1;
            centf[ 5 * 772 + d] = a2;  centf[ 4 * 772 + d] = tsum_reg - a2;
            centf[ 7 * 772 + d] = a3;  centf[ 6 * 772 + d] = tsum_reg - a3;
            centf[ 9 * 772 + d] = a4;  centf[ 8 * 772 + d] = tsum_reg - a4;
            centf[11 * 772 + d] = a5;  centf[10 * 772 + d] = tsum_reg - a5;
            centf[13 * 772 + d] = a6;  centf[12 * 772 + d] = tsum_reg - a6;
            centf[15 * 772 + d] = a7;  centf[14 * 772 + d] = tsum_reg - a7;
        }
        __syncthreads();

        // ==== normalize in place: wave r reads its centf row, reduces, scales
        {
            const int r = wave;
            float vals[12];
            float ss = 0.f;
#pragma unroll
            for (int j = 0; j < 12; ++j) {
                vals[j] = centf[r * 772 + lane + 64 * j];
                ss = fmaf(vals[j], vals[j], ss);
            }
            ss = waveReduceSum(ss);
            float iv = 1.0f / fmaxf(sqrtf(ss), 1e-12f);
#pragma unroll
            for (int j = 0; j < 12; ++j)
                centf[r * 772 + lane + 64 * j] = vals[j] * iv;
        }
        __syncthreads();   // cent ready; tbuf (incl. maskF overlay) free for next iter
    }

    // ---- scatter: vc[idx,0,0] += centroids_final[b,k,0,0] (c0 row, element 0)
    if (t < KC) {
        atomicAdd(delta + sidx[t], centf[(2 * t) * 772]);
    }
}

__global__ __launch_bounds__(1024) void vcnorm_kernel(
    const float* __restrict__ vc,
    const float* __restrict__ delta,
    float* __restrict__ out)          // (V, 2, D)
{
    const int t = threadIdx.x;
    const int lane = t & 63;
    const int wave = t >> 6;
    const int r = blockIdx.x * 16 + wave;     // row in [0, 2V)
    if (r >= 2 * VV) return;
    const int v = r >> 1;
    const int c = r & 1;
    const float* src = vc + (size_t)r * DD;
    float4 x[3];
#pragma unroll
    for (int j = 0; j < 3; ++j)
        x[j] = *(const float4*)(src + (lane + 64 * j) * 4);
    if (c == 0 && lane == 0) x[0].x += delta[v];
    float ss = 0.f;
#pragma unroll
    for (int j = 0; j < 3; ++j)
        ss += x[j].x * x[j].x + x[j].y * x[j].y + x[j].z * x[j].z + x[j].w * x[j].w;
    ss = waveReduceSum(ss);
    float iv = 1.0f / fmaxf(sqrtf(ss), 1e-12f);
    float* dst = out + (size_t)r * DD;
#pragma unroll
    for (int j = 0; j < 3; ++j) {
        float4 y = make_float4(x[j].x * iv, x[j].y * iv, x[j].z * iv, x[j].w * iv);
        *(float4*)(dst + (lane + 64 * j) * 4) = y;
    }
}

extern "C" void kernel_launch(void* const* d_in, const int* in_sizes, int n_in,
                              void* d_out, int out_size, void* d_ws, size_t ws_size,
                              hipStream_t stream) {
    const float* tokens = (const float*)d_in[0];
    const float* vc     = (const float*)d_in[1];
    const int*   topk   = (const int*)d_in[2];
    float* out          = (float*)d_out;
    float* assignments  = out;                                   // B*NT*KC floats
    float* vcnew        = out + (size_t)BB * NT * KC;            // V*2*D floats
    float* delta        = (float*)d_ws;                          // V floats

    hipMemsetAsync(delta, 0, VV * sizeof(float), stream);
    hipLaunchKernelGGL(kmeans_kernel, dim3(BB), dim3(1024), 0, stream,
                       tokens, vc, topk, assignments, delta);
    hipLaunchKernelGGL(vcnorm_kernel, dim3((2 * VV + 15) / 16), dim3(1024), 0, stream,
                       vc, delta, vcnew);
}